// Round 2
// baseline (369.397 us; speedup 1.0000x reference)
//
#include <hip/hip_runtime.h>

typedef __attribute__((ext_vector_type(8))) short bf16x8;
typedef __attribute__((ext_vector_type(4))) float f32x4;
typedef __attribute__((ext_vector_type(4))) unsigned short us4;

#define T_SEQ 2048
#define DMODEL 2048
#define NH 16
#define NKV 4
#define HD 128
#define NQ2 4096      /* NH*HD*2 */
#define NKVD 512      /* NKV*HD  */
#define ATT_SCALE 0.08838834764831845f

__device__ __forceinline__ float bf2f(unsigned short u) {
  union { unsigned int u; float f; } v; v.u = ((unsigned int)u) << 16; return v.f;
}
__device__ __forceinline__ unsigned short f2bf(float f) {
  union { float f; unsigned int u; } v; v.f = f;
  unsigned int u = v.u;
  return (unsigned short)((u + 0x7fffu + ((u >> 16) & 1u)) >> 16);
}
__device__ __forceinline__ f32x4 mfma16(bf16x8 a, bf16x8 b, f32x4 c) {
  return __builtin_amdgcn_mfma_f32_16x16x32_bf16(a, b, c, 0, 0, 0);
}

// ---------------- fp32 -> bf16 elementwise (hidden) ----------------
__global__ __launch_bounds__(256) void convert_x(const float* __restrict__ in,
                                                 unsigned short* __restrict__ out, int n4) {
  int i = blockIdx.x * 256 + threadIdx.x;
  if (i >= n4) return;
  float4 v = ((const float4*)in)[i];
  us4 o; o.x = f2bf(v.x); o.y = f2bf(v.y); o.z = f2bf(v.z); o.w = f2bf(v.w);
  ((us4*)out)[i] = o;
}

// ---------------- fp32 [K][N] -> bf16 [N][K] transpose ----------------
__global__ __launch_bounds__(256) void transpose_f32_to_bf16(
    const float* __restrict__ in, unsigned short* __restrict__ out, int K, int N) {
  __shared__ unsigned short tile[32][33];
  int nb = blockIdx.x * 32, kb = blockIdx.y * 32;
  int tx = threadIdx.x & 31, ty = threadIdx.x >> 5;
#pragma unroll
  for (int i = 0; i < 32; i += 8)
    tile[ty + i][tx] = f2bf(in[(size_t)(kb + ty + i) * N + nb + tx]);
  __syncthreads();
#pragma unroll
  for (int i = 0; i < 32; i += 8)
    out[(size_t)(nb + ty + i) * K + kb + tx] = tile[tx][ty + i];
}

// ---------------- bf16 V [T][NKV*HD] -> [NKV][HD][T] ----------------
__global__ __launch_bounds__(256) void transpose_v(const unsigned short* __restrict__ vbuf,
                                                   unsigned short* __restrict__ vTg) {
  __shared__ unsigned short tile[32][33];
  int tb = blockIdx.x * 32, db = blockIdx.y * 32, kvh = blockIdx.z;
  int tx = threadIdx.x & 31, ty = threadIdx.x >> 5;
#pragma unroll
  for (int i = 0; i < 32; i += 8)
    tile[ty + i][tx] = vbuf[(size_t)(tb + ty + i) * NKVD + kvh * HD + db + tx];
  __syncthreads();
#pragma unroll
  for (int i = 0; i < 32; i += 8)
    vTg[((size_t)kvh * HD + db + ty + i) * T_SEQ + tb + tx] = tile[tx][ty + i];
}

// ---------------- GEMM: C[M][N] = A[M][K] * B^T  (B stored [N][K]) ----------------
// 128x128 tile, 4 waves (2x2), each wave 64x64 via 4x4 16x16x32 MFMA frags.
template <typename OT>
__global__ __launch_bounds__(256) void gemm_bt(const unsigned short* __restrict__ A,
                                               const unsigned short* __restrict__ B,
                                               OT* __restrict__ C, int M, int N, int K) {
  __shared__ unsigned short As[128][40];
  __shared__ unsigned short Bs[128][40];
  const int tid = threadIdx.x;
  const int wave = tid >> 6, lane = tid & 63;
  const int wr = wave >> 1, wc = wave & 1;
  const int g = lane >> 4, lr = lane & 15;
  const int row0 = blockIdx.y * 128, col0 = blockIdx.x * 128;
  const int srow = tid >> 2, scol = (tid & 3) * 8;

  const unsigned short* Ap = A + (size_t)(row0 + srow) * K + scol;
  const unsigned short* Bp = B + (size_t)(col0 + srow) * K + scol;

  f32x4 acc[4][4] = {};

  for (int k0 = 0; k0 < K; k0 += 32) {
    bf16x8 a0 = *(const bf16x8*)(Ap + k0);
    bf16x8 a1 = *(const bf16x8*)(Ap + (size_t)64 * K + k0);
    bf16x8 b0 = *(const bf16x8*)(Bp + k0);
    bf16x8 b1 = *(const bf16x8*)(Bp + (size_t)64 * K + k0);
    __syncthreads();
    *(bf16x8*)(&As[srow][scol]) = a0;
    *(bf16x8*)(&As[srow + 64][scol]) = a1;
    *(bf16x8*)(&Bs[srow][scol]) = b0;
    *(bf16x8*)(&Bs[srow + 64][scol]) = b1;
    __syncthreads();

    bf16x8 af[4], bfr[4];
#pragma unroll
    for (int m = 0; m < 4; ++m) af[m] = *(const bf16x8*)(&As[wr * 64 + m * 16 + lr][g * 8]);
#pragma unroll
    for (int n = 0; n < 4; ++n) bfr[n] = *(const bf16x8*)(&Bs[wc * 64 + n * 16 + lr][g * 8]);
#pragma unroll
    for (int m = 0; m < 4; ++m)
#pragma unroll
      for (int n = 0; n < 4; ++n)
        acc[m][n] = mfma16(af[m], bfr[n], acc[m][n]);
  }

#pragma unroll
  for (int m = 0; m < 4; ++m)
#pragma unroll
    for (int n = 0; n < 4; ++n)
#pragma unroll
      for (int r = 0; r < 4; ++r) {
        int row = row0 + wr * 64 + m * 16 + g * 4 + r;
        int col = col0 + wc * 64 + n * 16 + lr;
        float v = acc[m][n][r];
        if constexpr (sizeof(OT) == 2) C[(size_t)row * N + col] = f2bf(v);
        else                            C[(size_t)row * N + col] = v;
      }
}

// ---------------- RMSNorm + RoPE for Q and K (IN PLACE) ----------------
// Q: reads/writes Qout q-half ([t][h*256 + d], d<128); gate half untouched.
// K: reads/writes Kraw [t][kh*128 + d].
__global__ __launch_bounds__(128) void rms_rope(
    unsigned short* __restrict__ qout, unsigned short* __restrict__ kraw,
    const float* __restrict__ cosb, const float* __restrict__ sinb,
    const float* __restrict__ qnw, const float* __restrict__ knw) {
  int t = blockIdx.x;
  int h = blockIdx.y;  // 0..15 q heads, 16..19 k heads
  int d = threadIdx.x; // 0..127
  bool isq = (h < NH);
  size_t addr = isq ? ((size_t)t * NQ2 + h * 256 + d)
                    : ((size_t)t * NKVD + (h - NH) * HD + d);
  unsigned short* buf = isq ? qout : kraw;
  float x = bf2f(buf[addr]);
  float ss = x * x;
#pragma unroll
  for (int mk = 1; mk < 64; mk <<= 1) ss += __shfl_xor(ss, mk, 64);
  __shared__ float red[2];
  __shared__ float xs[128];
  if ((d & 63) == 0) red[d >> 6] = ss;
  __syncthreads();
  float rstd = rsqrtf((red[0] + red[1]) * (1.0f / 128.0f) + 1e-6f);
  float w = isq ? qnw[d] : knw[d];
  float xn = x * rstd * w;
  xs[d] = xn;
  __syncthreads();
  float other = (d < 64) ? -xs[d + 64] : xs[d - 64];
  float c = cosb[(size_t)t * HD + d];
  float s = sinb[(size_t)t * HD + d];
  float ov = xn * c + other * s;
  buf[addr] = f2bf(ov);
}

// ---------------- Flash attention + gate ----------------
// block = (q-block of 64 rows, head); 4 waves x 16 q-rows; KV tile = 32.
// Q (normed+roped) and gate both live in qout: q at [t][h*256+d], gate at +128.
__global__ __launch_bounds__(256) void attn_kernel(
    const unsigned short* __restrict__ qout, const unsigned short* __restrict__ krope,
    const unsigned short* __restrict__ vTg,
    const int* __restrict__ seg, const int* __restrict__ pos,
    unsigned short* __restrict__ attnb) {
  const int h = blockIdx.y;
  const int qb = blockIdx.x;
  const int kvh = h >> 2;
  const int tid = threadIdx.x;
  const int wave = tid >> 6, lane = tid & 63;
  const int g = lane >> 4, lr = lane & 15;
  const int qrow0 = qb * 64 + wave * 16;

  __shared__ unsigned short Ks[32][136];
  __shared__ unsigned short Vt[128][40];
  __shared__ unsigned short Plds[4][16][40];

  bf16x8 qf[4];
#pragma unroll
  for (int c = 0; c < 4; ++c)
    qf[c] = *(const bf16x8*)(qout + (size_t)(qrow0 + lr) * NQ2 + h * 256 + c * 32 + g * 8);

  int myseg[4], mypos[4];
#pragma unroll
  for (int r = 0; r < 4; ++r) {
    int row = qrow0 + g * 4 + r;
    myseg[r] = seg[row];
    mypos[r] = pos[row];
  }

  float m_i[4] = {-1e30f, -1e30f, -1e30f, -1e30f};
  float l_i[4] = {0.f, 0.f, 0.f, 0.f};
  f32x4 oacc[8] = {};

  const int kv_end = qb * 64 + 64;
  for (int kv0 = 0; kv0 < kv_end; kv0 += 32) {
    __syncthreads();
    { // stage K tile [32][128]
      int r = tid >> 4, c = (tid & 15) * 8;
      *(bf16x8*)(&Ks[r][c])      = *(const bf16x8*)(krope + (size_t)(kv0 + r) * NKVD + kvh * HD + c);
      *(bf16x8*)(&Ks[r + 16][c]) = *(const bf16x8*)(krope + (size_t)(kv0 + r + 16) * NKVD + kvh * HD + c);
    }
    { // stage V^T tile [128][32] from pre-transposed vTg
      int d = tid >> 2, c = (tid & 3) * 8;
      *(bf16x8*)(&Vt[d][c])      = *(const bf16x8*)(vTg + ((size_t)kvh * HD + d) * T_SEQ + kv0 + c);
      *(bf16x8*)(&Vt[d + 64][c]) = *(const bf16x8*)(vTg + ((size_t)kvh * HD + d + 64) * T_SEQ + kv0 + c);
    }
    __syncthreads();

    // S = Q K^T : 16 x 32, two 16-col halves
    f32x4 sacc[2] = {};
#pragma unroll
    for (int cc = 0; cc < 2; ++cc)
#pragma unroll
      for (int c = 0; c < 4; ++c) {
        bf16x8 kf = *(const bf16x8*)(&Ks[cc * 16 + lr][c * 32 + g * 8]);
        sacc[cc] = mfma16(qf[c], kf, sacc[cc]);
      }

    int kvseg[2], kvpos[2];
#pragma unroll
    for (int cc = 0; cc < 2; ++cc) {
      kvseg[cc] = seg[kv0 + cc * 16 + lr];
      kvpos[cc] = pos[kv0 + cc * 16 + lr];
    }

    float p0v[4], p1v[4], fs[4];
#pragma unroll
    for (int r = 0; r < 4; ++r) {
      float x0 = sacc[0][r] * ATT_SCALE;
      float x1 = sacc[1][r] * ATT_SCALE;
      bool ok0 = (kvpos[0] <= mypos[r]) && (kvseg[0] == myseg[r]);
      bool ok1 = (kvpos[1] <= mypos[r]) && (kvseg[1] == myseg[r]);
      x0 = ok0 ? x0 : -1e30f;
      x1 = ok1 ? x1 : -1e30f;
      float tm = fmaxf(x0, x1);
#pragma unroll
      for (int mk = 1; mk < 16; mk <<= 1) tm = fmaxf(tm, __shfl_xor(tm, mk, 64));
      float mn = fmaxf(m_i[r], tm);
      float p0 = ok0 ? __expf(x0 - mn) : 0.0f;
      float p1 = ok1 ? __expf(x1 - mn) : 0.0f;
      float rs = p0 + p1;
#pragma unroll
      for (int mk = 1; mk < 16; mk <<= 1) rs += __shfl_xor(rs, mk, 64);
      float f = __expf(m_i[r] - mn);
      m_i[r] = mn;
      l_i[r] = l_i[r] * f + rs;
      fs[r] = f;
      p0v[r] = p0; p1v[r] = p1;
    }
#pragma unroll
    for (int n = 0; n < 8; ++n)
#pragma unroll
      for (int r = 0; r < 4; ++r) oacc[n][r] *= fs[r];

#pragma unroll
    for (int r = 0; r < 4; ++r) {
      Plds[wave][g * 4 + r][lr]      = f2bf(p0v[r]);
      Plds[wave][g * 4 + r][16 + lr] = f2bf(p1v[r]);
    }
    bf16x8 pf = *(const bf16x8*)(&Plds[wave][lr][g * 8]);
#pragma unroll
    for (int n = 0; n < 8; ++n) {
      bf16x8 vf = *(const bf16x8*)(&Vt[n * 16 + lr][g * 8]);
      oacc[n] = mfma16(pf, vf, oacc[n]);
    }
  }

  // epilogue: normalize, sigmoid-gate, store bf16
#pragma unroll
  for (int n = 0; n < 8; ++n)
#pragma unroll
    for (int r = 0; r < 4; ++r) {
      int row = qrow0 + g * 4 + r;
      int d = n * 16 + lr;
      float o = oacc[n][r] / l_i[r];
      float gv = bf2f(qout[(size_t)row * NQ2 + h * 256 + 128 + d]);
      float gate = 1.0f / (1.0f + __expf(-gv));
      attnb[(size_t)row * (NH * HD) + h * HD + d] = f2bf(o * gate);
    }
}

extern "C" void kernel_launch(void* const* d_in, const int* in_sizes, int n_in,
                              void* d_out, int out_size, void* d_ws, size_t ws_size,
                              hipStream_t stream) {
  const float* hidden = (const float*)d_in[0];
  const float* cosb   = (const float*)d_in[1];
  const float* sinb   = (const float*)d_in[2];
  const int*   seg    = (const int*)d_in[3];
  const int*   pos    = (const int*)d_in[4];
  const float* wq     = (const float*)d_in[5];
  const float* wk     = (const float*)d_in[6];
  const float* wv     = (const float*)d_in[7];
  const float* wo     = (const float*)d_in[8];
  const float* qnw    = (const float*)d_in[9];
  const float* knw    = (const float*)d_in[10];
  float* out = (float*)d_out;

  // Workspace layout — peak 48 MB with liveness-based aliasing:
  //   [0,8)    Xb (hidden bf16)            -> dead after V GEMM -> Attnb
  //   [8,24)   Wqt                         -> dead after Q GEMM -> Wot [8,16)
  //   [24,26)  Wkt                         -> dead after K GEMM -> VT  [24,26)
  //   [26,28)  Wvt
  //   [28,44)  Qout (q normed/roped in place; gate half intact)
  //   [44,46)  Kraw (normed/roped in place)
  //   [46,48)  Vbuf
  char* ws = (char*)d_ws;
  const size_t MB = (size_t)1 << 20;
  unsigned short* Xb    = (unsigned short*)(ws + 0 * MB);
  unsigned short* Attnb = (unsigned short*)(ws + 0 * MB);   // alias Xb
  unsigned short* Wqt   = (unsigned short*)(ws + 8 * MB);
  unsigned short* Wot   = (unsigned short*)(ws + 8 * MB);   // alias Wqt
  unsigned short* Wkt   = (unsigned short*)(ws + 24 * MB);
  unsigned short* VT    = (unsigned short*)(ws + 24 * MB);  // alias Wkt
  unsigned short* Wvt   = (unsigned short*)(ws + 26 * MB);
  unsigned short* Qout  = (unsigned short*)(ws + 28 * MB);
  unsigned short* Kraw  = (unsigned short*)(ws + 44 * MB);
  unsigned short* Vbuf  = (unsigned short*)(ws + 46 * MB);

  convert_x<<<4096, 256, 0, stream>>>(hidden, Xb, (DMODEL * T_SEQ) / 4);
  transpose_f32_to_bf16<<<dim3(NQ2 / 32, DMODEL / 32), 256, 0, stream>>>(wq, Wqt, DMODEL, NQ2);
  transpose_f32_to_bf16<<<dim3(NKVD / 32, DMODEL / 32), 256, 0, stream>>>(wk, Wkt, DMODEL, NKVD);
  transpose_f32_to_bf16<<<dim3(NKVD / 32, DMODEL / 32), 256, 0, stream>>>(wv, Wvt, DMODEL, NKVD);

  gemm_bt<unsigned short><<<dim3(NQ2 / 128, T_SEQ / 128), 256, 0, stream>>>(Xb, Wqt, Qout, T_SEQ, NQ2, DMODEL);
  gemm_bt<unsigned short><<<dim3(NKVD / 128, T_SEQ / 128), 256, 0, stream>>>(Xb, Wkt, Kraw, T_SEQ, NKVD, DMODEL);
  gemm_bt<unsigned short><<<dim3(NKVD / 128, T_SEQ / 128), 256, 0, stream>>>(Xb, Wvt, Vbuf, T_SEQ, NKVD, DMODEL);

  // Wqt dead now -> transpose Wo into its region. Wkt dead -> VT.
  transpose_f32_to_bf16<<<dim3(DMODEL / 32, DMODEL / 32), 256, 0, stream>>>(wo, Wot, DMODEL, DMODEL);

  rms_rope<<<dim3(T_SEQ, 20), 128, 0, stream>>>(Qout, Kraw, cosb, sinb, qnw, knw);
  transpose_v<<<dim3(T_SEQ / 32, HD / 32, NKV), 256, 0, stream>>>(Vbuf, VT);

  attn_kernel<<<dim3(T_SEQ / 64, NH), 256, 0, stream>>>(Qout, Kraw, VT, seg, pos, Attnb);

  gemm_bt<float><<<dim3(DMODEL / 128, T_SEQ / 128), 256, 0, stream>>>(Attnb, Wot, out, T_SEQ, DMODEL, DMODEL);
}